// Round 7
// baseline (288.012 us; speedup 1.0000x reference)
//
#include <hip/hip_runtime.h>
#include <hip/hip_bf16.h>

// ---------------- types ----------------
typedef __attribute__((ext_vector_type(8))) short bf16x8;   // 8 bf16 (4 VGPRs)
typedef __attribute__((ext_vector_type(4))) float f32x4;    // MFMA accum

__device__ __forceinline__ unsigned short f2b(float f) {
    unsigned int u = __builtin_bit_cast(unsigned int, f);
    u += 0x7FFFu + ((u >> 16) & 1u);          // RNE
    return (unsigned short)(u >> 16);
}
__device__ __forceinline__ float b2f(unsigned short h) {
    unsigned int u = ((unsigned int)h) << 16;
    return __builtin_bit_cast(float, u);
}

// ---------------- workspace layout (byte offsets) ----------------
// qkv1 bf16 [8][384][16384]                100,663,296 B
// slot2: Vg bf16 [8][128][16384] (33.5MB)  written by dw_v_gate
// wbf  bf16 [384][128]
// G    f32  [8][8][16][16]   (zeroed in prep)
// nqk  f32  [8][256]         (zeroed in prep, contiguous after G)
// CtBo bf16 [8][128][128]
#define OFFB_QKV1 0L
#define OFFB_SLOT2 100663296L
#define OFFB_WBF  201326592L
#define OFFB_G    201424896L
#define OFFB_NQK  201490432L
#define OFFB_CTB  201564160L

// ---------------- prep: w_qkv fp32 -> bf16; zero G+nqk ----------------
__global__ __launch_bounds__(256) void prep_w_zero(const float* __restrict__ w,
                                                   unsigned short* __restrict__ wbf,
                                                   float* __restrict__ Gz)
{
    if (blockIdx.x < 48) {
        int e = blockIdx.x * 256 + threadIdx.x;       // < 12288
        float4 v = *(const float4*)&w[e * 4];
        unsigned int p0 = (unsigned int)f2b(v.x) | ((unsigned int)f2b(v.y) << 16);
        unsigned int p1 = (unsigned int)f2b(v.z) | ((unsigned int)f2b(v.w) << 16);
        *(uint2*)&wbf[e * 4] = make_uint2(p0, p1);
    } else {
        // zero G (16384 f) + nqk (2048 f) = 18432 floats
        for (int i = threadIdx.x; i < 18432; i += 256) Gz[i] = 0.f;
    }
}

// ---------------- K1 fused: in-kernel x transpose + MFMA GEMM ---------------
// qkv1[b][m][n] = sum_c wbf[m][c] * x[b][c][n];  grid (128 n-tiles, 8 b).
// B (x tile) transposed fp32->bf16 in LDS once; 3 m-tiles looped, As reused
// as the bf16 C staging buffer for coalesced stores.
__global__ __launch_bounds__(256) void k1_fused(
    const unsigned short* __restrict__ wbf,   // [384][128] bf16
    const float* __restrict__ x,              // [8][128][16384] fp32
    unsigned short* __restrict__ qkv1)        // [8][384][16384] bf16
{
    const int b = blockIdx.y, n0 = blockIdx.x * 128;
    __shared__ unsigned short Bs[128][136];
    __shared__ unsigned short As[128][136];
    __shared__ float sfl[32][65];
    const int tid = threadIdx.x;

    // ---- transpose-stage x tile -> Bs[n][c] bf16 (8 sub-tiles of 32c x 64n)
    const float* xb = x + (long)b * 128 * 16384 + n0;
#pragma unroll 1
    for (int it = 0; it < 8; ++it) {
        const int c0 = (it & 3) * 32, nb0 = (it >> 2) * 64;
        {
            int c = tid >> 3, n8 = (tid & 7) * 8;
            *(float4*)&sfl[c][n8]     = *(const float4*)&xb[(long)(c0 + c) * 16384 + nb0 + n8];
            *(float4*)&sfl[c][n8 + 4] = *(const float4*)&xb[(long)(c0 + c) * 16384 + nb0 + n8 + 4];
        }
        __syncthreads();
        {
            int n = tid >> 2, cg = (tid & 3) * 8;
            unsigned int p[4];
#pragma unroll
            for (int j = 0; j < 4; ++j)
                p[j] = (unsigned int)f2b(sfl[cg + 2*j][n]) | ((unsigned int)f2b(sfl[cg + 2*j + 1][n]) << 16);
            *(uint4*)&Bs[nb0 + n][c0 + cg] = make_uint4(p[0], p[1], p[2], p[3]);
        }
        __syncthreads();
    }

    const int l  = tid & 63;
    const int w  = tid >> 6;
    const int mb = (w & 1) * 64, nb = (w >> 1) * 64;
    const int lr = l & 15, lg = l >> 4;

#pragma unroll 1
    for (int mt = 0; mt < 3; ++mt) {
        const unsigned short* Ab = wbf + (long)(mt * 128) * 128;
#pragma unroll
        for (int i = 0; i < 8; ++i) {
            int ch = tid + i * 256;
            int row = ch >> 4, cg = (ch & 15) * 8;
            *(uint4*)&As[row][cg] = *(const uint4*)&Ab[row * 128 + cg];
        }
        __syncthreads();

        f32x4 acc[4][4];
        const f32x4 zero = {0.f, 0.f, 0.f, 0.f};
#pragma unroll
        for (int mi = 0; mi < 4; ++mi)
#pragma unroll
            for (int ni = 0; ni < 4; ++ni) acc[mi][ni] = zero;

#pragma unroll
        for (int kk = 0; kk < 128; kk += 32) {
            bf16x8 af[4], bfr[4];
#pragma unroll
            for (int mi = 0; mi < 4; ++mi)
                af[mi] = *(const bf16x8*)&As[mb + mi * 16 + lr][kk + lg * 8];
#pragma unroll
            for (int ni = 0; ni < 4; ++ni)
                bfr[ni] = *(const bf16x8*)&Bs[nb + ni * 16 + lr][kk + lg * 8];
#pragma unroll
            for (int mi = 0; mi < 4; ++mi)
#pragma unroll
                for (int ni = 0; ni < 4; ++ni)
                    acc[mi][ni] = __builtin_amdgcn_mfma_f32_16x16x32_bf16(
                        af[mi], bfr[ni], acc[mi][ni], 0, 0, 0);
        }

        __syncthreads();
        unsigned short* ct = &As[0][0];        // reuse As as flat [128][128] C tile
#pragma unroll
        for (int mi = 0; mi < 4; ++mi)
#pragma unroll
            for (int ni = 0; ni < 4; ++ni)
#pragma unroll
                for (int r = 0; r < 4; ++r)
                    ct[(mb + mi * 16 + lg * 4 + r) * 128 + nb + ni * 16 + lr] =
                        f2b(acc[mi][ni][r]);
        __syncthreads();
        unsigned short* Cg = qkv1 + ((long)b * 384 + mt * 128) * 16384 + n0;
#pragma unroll
        for (int i = 0; i < 8; ++i) {
            int ch = tid + i * 256;
            int row = ch >> 4, cg = (ch & 15) * 8;
            *(uint4*)&Cg[(long)row * 16384 + cg] = *(const uint4*)&ct[row * 128 + cg];
        }
        __syncthreads();                       // As reused next m-tile
    }
}

// ---------------- fused dwconv(q,k) + norms + gram MFMA --------------------
// grid (16 strips of 8 rows, 8 heads, 8 b), 256 threads (4 waves).
// Channel-major staging st[ch][y][s], s = x+1 (halo at s=0,129); strides give
// 16B-aligned ds_read_b128 rows with <=2-way bank aliasing.
#define CHS 1416   // u16 per channel: 2832 B, mult of 16, ==16 mod 128
#define YS  136    // u16 per staged row: 272 B, mult of 16
__global__ __launch_bounds__(256) void dw_qk_gram(
    const unsigned short* __restrict__ qkv1, const float* __restrict__ wdw,
    float* __restrict__ G, float* __restrict__ nqk)
{
    const int strip = blockIdx.x, hd = blockIdx.y, b = blockIdx.z;
    const int y0 = strip * 8;
    const int tid = threadIdx.x;
    const int l = tid & 63, w = tid >> 6;
    const int lr = l & 15, lg = l >> 4;

    __shared__ unsigned short st[16 * CHS];
    __shared__ float sg[4][16][16];

    // zero x-halo (s=0 and s=129 for every ch,y)
    if (tid < 160) {
        int y = tid >> 4, c = tid & 15;
        st[c * CHS + y * YS + 0]   = 0;
        st[c * CHS + y * YS + 129] = 0;
    }

    const int sch = tid & 15;       // staged channel
    const int sxc = tid >> 4;       // x-chunk (8 halfs each)

    bf16x8 af[8];
    f32x4 acc = {0.f, 0.f, 0.f, 0.f};
    float qn = 0.f, kn = 0.f;

    for (int op = 0; op < 2; ++op) {
        const int chbase = op * 128 + hd * 16;
        __syncthreads();                       // halo done / prior frag reads done
        const unsigned short* src = qkv1 + ((long)b * 384 + chbase + sch) * 16384;
        unsigned short* dst = &st[sch * CHS + sxc * 8 + 1];
#pragma unroll
        for (int y = 0; y < 10; ++y) {
            int yy = y0 + y - 1;
            uint4 v = make_uint4(0, 0, 0, 0);
            if (yy >= 0 && yy < 128) v = *(const uint4*)&src[yy * 128 + sxc * 8];
            unsigned short* d = dst + y * YS;
            d[0] = (unsigned short)(v.x);
            d[1] = (unsigned short)(v.x >> 16);
            d[2] = (unsigned short)(v.y);
            d[3] = (unsigned short)(v.y >> 16);
            d[4] = (unsigned short)(v.z);
            d[5] = (unsigned short)(v.z >> 16);
            d[6] = (unsigned short)(v.w);
            d[7] = (unsigned short)(v.w >> 16);
        }
        __syncthreads();

        float wv[9];
#pragma unroll
        for (int j = 0; j < 9; ++j) wv[j] = wdw[(chbase + lr) * 9 + j];

#pragma unroll
        for (int j = 0; j < 8; ++j) {
            const int yb = 2 * w + (j >> 2);          // staged row of tap -1
            const int x0 = (j & 3) * 32 + lg * 8;     // shifted tap base (s units)
            const unsigned short* rb = &st[lr * CHS + yb * YS + x0];
            float r0[10], r1[10], r2[10];
#pragma unroll
            for (int rr = 0; rr < 3; ++rr) {
                float* r = (rr == 0) ? r0 : (rr == 1) ? r1 : r2;
                const unsigned short* p = rb + rr * YS;
                bf16x8 a8 = *(const bf16x8*)p;                   // ds_read_b128
                unsigned int t = *(const unsigned int*)(p + 8);  // ds_read_b32
#pragma unroll
                for (int i = 0; i < 8; ++i) r[i] = b2f((unsigned short)a8[i]);
                r[8] = b2f((unsigned short)(t & 0xFFFF));
                r[9] = b2f((unsigned short)(t >> 16));
            }
            bf16x8 fr;
            float nrm = 0.f;
#pragma unroll
            for (int i = 0; i < 8; ++i) {
                float a = 0.f;
                a = fmaf(wv[0], r0[i], a); a = fmaf(wv[1], r0[i+1], a); a = fmaf(wv[2], r0[i+2], a);
                a = fmaf(wv[3], r1[i], a); a = fmaf(wv[4], r1[i+1], a); a = fmaf(wv[5], r1[i+2], a);
                a = fmaf(wv[6], r2[i], a); a = fmaf(wv[7], r2[i+1], a); a = fmaf(wv[8], r2[i+2], a);
                unsigned short hh = f2b(a);
                fr[i] = (short)hh;
                float f = b2f(hh);                    // norms on rounded values
                nrm = fmaf(f, f, nrm);
            }
            if (op == 0) { af[j] = fr; qn += nrm; }
            else {
                kn += nrm;
                acc = __builtin_amdgcn_mfma_f32_16x16x32_bf16(af[j], fr, acc, 0, 0, 0);
            }
        }
    }

    // norms: reduce across lg groups (lanes sharing lr)
    qn += __shfl_xor(qn, 16); qn += __shfl_xor(qn, 32);
    kn += __shfl_xor(kn, 16); kn += __shfl_xor(kn, 32);
    if (l < 16) {
        atomicAdd(&nqk[b * 256 + hd * 16 + lr], qn);
        atomicAdd(&nqk[b * 256 + 128 + hd * 16 + lr], kn);
    }

    // gram: reduce 4 waves then atomic
#pragma unroll
    for (int r = 0; r < 4; ++r) sg[w][lg * 4 + r][lr] = acc[r];
    __syncthreads();
    const int row = tid >> 4, col = tid & 15;
    float v = sg[0][row][col] + sg[1][row][col] + sg[2][row][col] + sg[3][row][col];
    atomicAdd(&G[(((long)b * 8 + hd) * 16 + row) * 16 + col], v);
}

// ---------------- depthwise 3x3 (v) + illu gating -> Vg bf16 [c][n] --------
__global__ __launch_bounds__(256) void dw_v_gate(
    const unsigned short* __restrict__ qkv1, const float* __restrict__ wdw,
    const float* __restrict__ illu, unsigned short* __restrict__ Vg)
{
    const int b = blockIdx.z, c = blockIdx.y;
    const int ch = 256 + c;
    const int y0 = blockIdx.x * 16;
    const int tid = threadIdx.x;
    __shared__ float lds[18][136];
    const unsigned short* in = qkv1 + ((long)b * 384 + ch) * 16384;

    float wv[9];
#pragma unroll
    for (int j = 0; j < 9; ++j) wv[j] = wdw[ch * 9 + j];

#pragma unroll
    for (int i = 0; i < 2; ++i) {
        int chk = tid + i * 256;
        if (chk < 288) {
            int row = chk >> 4, xg = (chk & 15) * 8;
            int yy = y0 + row - 1;
            float f[8];
            if (yy >= 0 && yy < 128) {
                uint4 v = *(const uint4*)&in[yy * 128 + xg];
                unsigned int uu[4] = {v.x, v.y, v.z, v.w};
#pragma unroll
                for (int j = 0; j < 4; ++j) {
                    f[2*j]   = __builtin_bit_cast(float, uu[j] << 16);
                    f[2*j+1] = __builtin_bit_cast(float, uu[j] & 0xFFFF0000u);
                }
            } else {
#pragma unroll
                for (int j = 0; j < 8; ++j) f[j] = 0.f;
            }
            *(float4*)&lds[row][xg + 4] = make_float4(f[0], f[1], f[2], f[3]);
            *(float4*)&lds[row][xg + 8] = make_float4(f[4], f[5], f[6], f[7]);
        }
    }
    if (tid < 18) lds[tid][3] = 0.f;
    else if (tid < 50 && tid >= 32) lds[tid - 32][132] = 0.f;
    __syncthreads();

    const int x  = tid & 127;
    const int rt = (tid >> 7) * 8;            // 0 or 8
    float c0[10], c1[10], c2[10];
#pragma unroll
    for (int t = 0; t < 10; ++t) {
        c0[t] = lds[rt + t][x + 3];
        c1[t] = lds[rt + t][x + 4];
        c2[t] = lds[rt + t][x + 5];
    }
    const float* ib = illu + ((long)b * 128 + c) * 16384 + y0 * 128;
    unsigned short* ob = Vg + ((long)b * 128 + c) * 16384 + y0 * 128;
#pragma unroll
    for (int rr = 0; rr < 8; ++rr) {
        float a = 0.f;
        a = fmaf(wv[0], c0[rr],     a); a = fmaf(wv[1], c1[rr],     a); a = fmaf(wv[2], c2[rr],     a);
        a = fmaf(wv[3], c0[rr + 1], a); a = fmaf(wv[4], c1[rr + 1], a); a = fmaf(wv[5], c2[rr + 1], a);
        a = fmaf(wv[6], c0[rr + 2], a); a = fmaf(wv[7], c1[rr + 2], a); a = fmaf(wv[8], c2[rr + 2], a);
        int ry = rt + rr;
        ob[ry * 128 + x] = f2b(a * ib[ry * 128 + x]);
    }
}

// ------ fused softmax + compose: CtBo[b][o][D] ------------------------------
__global__ __launch_bounds__(256) void softmax_compose(
    const float* __restrict__ G, const float* __restrict__ nqk,
    const float* __restrict__ temp, const float* __restrict__ wproj,
    unsigned short* __restrict__ CtBo)
{
    const int b = blockIdx.x;
    const int tid = threadIdx.x;
    __shared__ float sa[8][16][16];
    if (tid < 128) {
        const int hd = tid >> 4, r = tid & 15;
        const float tv = temp[hd];
        const float* g = G + ((long)(b * 8 + hd) * 16 + r) * 16;
        float mq = fmaxf(sqrtf(nqk[b * 256 + hd * 16 + r]), 1e-12f);
        float L[16];
        float mx = -1e30f;
#pragma unroll
        for (int d = 0; d < 16; ++d) {
            float mk = fmaxf(sqrtf(nqk[b * 256 + 128 + hd * 16 + d]), 1e-12f);
            L[d] = g[d] * tv / (mq * mk);
            mx = fmaxf(mx, L[d]);
        }
        float s = 0.f;
#pragma unroll
        for (int d = 0; d < 16; ++d) { L[d] = expf(L[d] - mx); s += L[d]; }
        float inv = 1.f / s;
#pragma unroll
        for (int d = 0; d < 16; ++d) sa[hd][r][d] = L[d] * inv;
    }
    __syncthreads();
#pragma unroll 1
    for (int e = tid; e < 16384; e += 256) {
        const int o = e >> 7, D = e & 127;
        const int hd2 = D >> 4, d = D & 15;
        const float* wr = wproj + o * 128 + hd2 * 16;
        float s = 0.f;
#pragma unroll
        for (int c2 = 0; c2 < 16; ++c2) s = fmaf(wr[c2], sa[hd2][c2][d], s);
        CtBo[((long)b * 128 + o) * 128 + D] = f2b(s);
    }
}

// ------ K6: out[b][o][n] = sum_D CtBo[b][o][D] * Vg[b][D][n] ---------------
__global__ __launch_bounds__(256) void mfma_k6(
    const unsigned short* __restrict__ CtBo, const unsigned short* __restrict__ Vg,
    float* __restrict__ out)
{
    const int b  = blockIdx.y;
    const int n0 = blockIdx.x * 128;
    __shared__ unsigned short As[128][136];
    __shared__ unsigned short Bs[128][136];
    __shared__ float sfl[32][65];
    const int tid = threadIdx.x;

    const unsigned short* Ab = CtBo + (long)b * 16384;
#pragma unroll
    for (int i = 0; i < 8; ++i) {
        int ch = tid + i * 256;
        int row = ch >> 4, cg = (ch & 15) * 8;
        *(uint4*)&As[row][cg] = *(const uint4*)&Ab[row * 128 + cg];
    }

    const unsigned short* Vb = Vg + (long)b * 128 * 16384;
#pragma unroll 1
    for (int it = 0; it < 8; ++it) {
        const int c0 = (it & 3) * 32, nb0 = (it >> 2) * 64;
        {
            int c = tid >> 3, n8 = (tid & 7) * 8;
            uint4 v = *(const uint4*)&Vb[(long)(c0 + c) * 16384 + n0 + nb0 + n8];
            unsigned int uu[4] = {v.x, v.y, v.z, v.w};
#pragma unroll
            for (int j = 0; j < 4; ++j) {
                sfl[c][n8 + 2*j]     = __builtin_bit_cast(float, uu[j] << 16);
                sfl[c][n8 + 2*j + 1] = __builtin_bit_cast(float, uu[j] & 0xFFFF0000u);
            }
        }
        __syncthreads();
        {
            int n = tid >> 2, cg = (tid & 3) * 8;
            unsigned int p[4];
#pragma unroll
            for (int j = 0; j < 4; ++j)
                p[j] = (unsigned int)f2b(sfl[cg + 2*j][n]) | ((unsigned int)f2b(sfl[cg + 2*j + 1][n]) << 16);
            *(uint4*)&Bs[nb0 + n][c0 + cg] = make_uint4(p[0], p[1], p[2], p[3]);
        }
        __syncthreads();
    }

    const int l  = tid & 63;
    const int w  = tid >> 6;
    const int mb = (w & 1) * 64, nb = (w >> 1) * 64;
    const int lr = l & 15, lg = l >> 4;

    f32x4 acc[4][4];
    const f32x4 zero = {0.f, 0.f, 0.f, 0.f};
#pragma unroll
    for (int mi = 0; mi < 4; ++mi)
#pragma unroll
        for (int ni = 0; ni < 4; ++ni) acc[mi][ni] = zero;

#pragma unroll
    for (int kk = 0; kk < 128; kk += 32) {
        bf16x8 af[4], bfr[4];
#pragma unroll
        for (int mi = 0; mi < 4; ++mi)
            af[mi] = *(const bf16x8*)&As[mb + mi * 16 + lr][kk + lg * 8];
#pragma unroll
        for (int ni = 0; ni < 4; ++ni)
            bfr[ni] = *(const bf16x8*)&Bs[nb + ni * 16 + lr][kk + lg * 8];
#pragma unroll
        for (int mi = 0; mi < 4; ++mi)
#pragma unroll
            for (int ni = 0; ni < 4; ++ni)
                acc[mi][ni] = __builtin_amdgcn_mfma_f32_16x16x32_bf16(
                    af[mi], bfr[ni], acc[mi][ni], 0, 0, 0);
    }

    float* Cg = out + ((long)b * 128) * 16384 + n0;
#pragma unroll
    for (int mi = 0; mi < 4; ++mi)
#pragma unroll
        for (int ni = 0; ni < 4; ++ni)
#pragma unroll
            for (int r = 0; r < 4; ++r)
                Cg[(long)(mb + mi * 16 + lg * 4 + r) * 16384 + nb + ni * 16 + lr] =
                    acc[mi][ni][r];
}

extern "C" void kernel_launch(void* const* d_in, const int* in_sizes, int n_in,
                              void* d_out, int out_size, void* d_ws, size_t ws_size,
                              hipStream_t stream)
{
    const float* x     = (const float*)d_in[0];
    const float* illu  = (const float*)d_in[1];
    const float* wqkv  = (const float*)d_in[2];
    const float* wdw   = (const float*)d_in[3];
    const float* wproj = (const float*)d_in[4];
    const float* temp  = (const float*)d_in[5];
    float* out = (float*)d_out;
    char*  wsb = (char*)d_ws;

    unsigned short* qkv1 = (unsigned short*)(wsb + OFFB_QKV1);
    unsigned short* Vg   = (unsigned short*)(wsb + OFFB_SLOT2);
    unsigned short* wbf  = (unsigned short*)(wsb + OFFB_WBF);
    float* G    = (float*)(wsb + OFFB_G);
    float* nqk  = (float*)(wsb + OFFB_NQK);
    unsigned short* CtBo = (unsigned short*)(wsb + OFFB_CTB);

    // prep: w->bf16 + zero G/nqk
    hipLaunchKernelGGL(prep_w_zero, dim3(49), dim3(256), 0, stream, wqkv, wbf, G);
    // K1 fused: qkv1 = Wqkv @ x (in-kernel x transpose)
    hipLaunchKernelGGL(k1_fused, dim3(128, 8), dim3(256), 0, stream,
                       wbf, x, qkv1);
    // dw(v) + gating -> Vg
    hipLaunchKernelGGL(dw_v_gate, dim3(8, 128, 8), dim3(256), 0, stream,
                       qkv1, wdw, illu, Vg);
    // fused dw(q,k) + norms + gram
    hipLaunchKernelGGL(dw_qk_gram, dim3(16, 8, 8), dim3(256), 0, stream,
                       qkv1, wdw, G, nqk);
    // softmax + compose -> CtBo
    hipLaunchKernelGGL(softmax_compose, dim3(8), dim3(256), 0, stream,
                       G, nqk, temp, wproj, CtBo);
    // K6: out = CtBo @ Vg (in-kernel V transpose)
    hipLaunchKernelGGL(mfma_k6, dim3(128, 8), dim3(256), 0, stream,
                       CtBo, Vg, out);
}